// Round 15
// baseline (28.834 us; speedup 1.0000x reference)
//
#include <hip/hip_runtime.h>

#define DIM   128
#define PLANE (DIM*DIM)
#define TD    16

typedef float vfloat4 __attribute__((ext_vector_type(4)));
typedef __attribute__((address_space(3))) char as3_char;
typedef const __attribute__((address_space(1))) char as1_char;

// ds_read_b128 with literal byte offset; opaque to compiler (no auto-waits).
#define DSR(d, SBASE, RB) \
    asm volatile("ds_read_b128 %0, %1 offset:" #RB : "=v"(d) : "v"(SBASE))
// counted vmcnt (never 0 in steady state) + hard scheduling fence (rule #18)
#define WAITVM(N) \
    asm volatile("s_waitcnt vmcnt(" #N ")" ::: "memory"); \
    __builtin_amdgcn_sched_barrier(0)
#define WAITLG \
    asm volatile("s_waitcnt lgkmcnt(0)" ::: "memory"); \
    __builtin_amdgcn_sched_barrier(0)

__global__ __launch_bounds__(256, 2) void conv3d_circ_ldsp(
    const float* __restrict__ x, const float* __restrict__ kern,
    float* __restrict__ out)
{
    // 4 waves x 3 slots x (6 rows x 128 f32 = 3072 B) — wave-private, no barriers
    __shared__ char smem[4 * 3 * 3072];

    const int tid = threadIdx.x;
    const int bid = blockIdx.x;
    const int b  = bid >> 6;          // 8 batches (8 ht x 8 dt)
    const int ht = (bid >> 3) & 7;    // 8 h-tiles of 16 rows
    const int dt = bid & 7;           // 8 d-chunks of 16 planes
    const int h0 = ht * 16;
    const int d0 = dt * TD;

    const int wv   = tid >> 6;        // wave id 0..3
    const int lane = tid & 63;
    const int hp   = (tid >> 5) & 1;  // which h-pair within the wave
    const int wq   = (lane & 31) * 4;
    const int hg   = h0 + (tid >> 5) * 2;        // output rows hg, hg+1
    const int lleft  = (lane & 32) | ((lane - 1) & 31);
    const int lright = (lane & 32) | ((lane + 1) & 31);
    const int rbase  = h0 + 4 * wv - 1;          // first of 6 rows this wave stages

    // per-lane global element offset within a plane for gload instr k
    int goff[3];
#pragma unroll
    for (int k = 0; k < 3; ++k) {
        const int u = k * 64 + lane;             // 16B unit index in 3KB slice
        goff[k] = (((rbase + (u >> 5)) & (DIM - 1)) * DIM) + ((u & 31) * 4);
    }

    as3_char* lwave = (as3_char*)smem + wv * 9216;
    const int rd_base = (int)(size_t)((as3_char*)smem)
                      + wv * 9216 + hp * 1024 + (lane & 31) * 16;
    const int sb0 = rd_base, sb1 = rd_base + 3072, sb2 = rd_base + 6144;

    float K0[9], K1[9], K2[9];
#pragma unroll
    for (int i = 0; i < 9; ++i) { K0[i] = kern[i]; K1[i] = kern[9 + i]; K2[i] = kern[18 + i]; }

    const float* xb = x + (size_t)b * (DIM * PLANE);
    float* optr = out + (size_t)b * (DIM * PLANE) + (size_t)d0 * PLANE
                + (size_t)hg * DIM + wq;         // store cursor, += PLANE per store

    vfloat4 cur[4];
    float accA[2][4], accB[2][4];
#pragma unroll
    for (int r = 0; r < 2; ++r)
#pragma unroll
        for (int j = 0; j < 4; ++j) { accA[r][j] = 0.f; accB[r][j] = 0.f; }

#define GLOAD(SLOT, PP)                                                       \
    {                                                                         \
        const float* xp_ = xb + (size_t)(((PP) & (DIM - 1)) * PLANE);         \
        _Pragma("unroll") for (int k = 0; k < 3; ++k)                         \
            __builtin_amdgcn_global_load_lds(                                 \
                (as1_char*)(const char*)(xp_ + goff[k]),                      \
                (as3_char*)(lwave + (SLOT) * 3072 + k * 1024), 16, 0, 0);     \
    }

    // Step consumes plane p (slot RS), prefetches plane p+2 (slot WS).
    // K2 -> out(p-1), K1 -> out(p), K0 -> out(p+1).
#define STEP(RS, WS, VM, DOLOAD, DOSTORE)                                     \
    {                                                                         \
        if (DOLOAD) GLOAD(WS, p + 2);                                         \
        WAITVM(VM);                                                           \
        DSR(cur[0], sb##RS, 0);                                               \
        DSR(cur[1], sb##RS, 512);                                             \
        DSR(cur[2], sb##RS, 1024);                                            \
        DSR(cur[3], sb##RS, 1536);                                            \
        WAITLG;                                                               \
        float e[4][6];                                                        \
        _Pragma("unroll") for (int rr = 0; rr < 4; ++rr) {                    \
            e[rr][0] = __shfl(cur[rr][3], lleft);                             \
            e[rr][1] = cur[rr][0]; e[rr][2] = cur[rr][1];                     \
            e[rr][3] = cur[rr][2]; e[rr][4] = cur[rr][3];                     \
            e[rr][5] = __shfl(cur[rr][0], lright);                            \
        }                                                                     \
        float c0[2][4];                                                       \
        _Pragma("unroll") for (int r = 0; r < 2; ++r)                         \
        _Pragma("unroll") for (int j = 0; j < 4; ++j) c0[r][j] = 0.f;         \
        _Pragma("unroll") for (int ch = 0; ch < 3; ++ch)                      \
        _Pragma("unroll") for (int cw = 0; cw < 3; ++cw) {                    \
            const float k0 = K0[ch * 3 + cw];                                 \
            const float k1 = K1[ch * 3 + cw];                                 \
            const float k2 = K2[ch * 3 + cw];                                 \
            _Pragma("unroll") for (int r = 0; r < 2; ++r)                     \
            _Pragma("unroll") for (int j = 0; j < 4; ++j) {                   \
                const float xv = e[r + ch][j + cw];                           \
                accA[r][j] = fmaf(k2, xv, accA[r][j]);                        \
                accB[r][j] = fmaf(k1, xv, accB[r][j]);                        \
                c0[r][j]   = fmaf(k0, xv, c0[r][j]);                          \
            }                                                                 \
        }                                                                     \
        if (DOSTORE) {                                                        \
            _Pragma("unroll") for (int r = 0; r < 2; ++r) {                   \
                vfloat4 v;                                                    \
                v.x = accA[r][0]; v.y = accA[r][1];                           \
                v.z = accA[r][2]; v.w = accA[r][3];                           \
                __builtin_nontemporal_store(v, (vfloat4*)(optr + r * DIM));   \
            }                                                                 \
            optr += PLANE;                                                    \
        }                                                                     \
        _Pragma("unroll") for (int r = 0; r < 2; ++r)                        \
        _Pragma("unroll") for (int j = 0; j < 4; ++j)                         \
            { accA[r][j] = accB[r][j]; accB[r][j] = c0[r][j]; }               \
        ++p;                                                                  \
    }

    int p = d0 - 1;
    GLOAD(0, d0 - 1);                 // slot0 <- plane d0-1
    GLOAD(1, d0);                     // slot1 <- plane d0
    // vmcnt accounting: N = VMEM ops issued after the awaited plane's 3 gloads
    STEP(0, 2, 6,  true,  false);     // read d0-1; gload d0+1
    STEP(1, 0, 6,  true,  false);     // read d0  ; gload d0+2
    STEP(2, 1, 6,  true,  true );     // read d0+1; gload d0+3; store d0
    STEP(0, 2, 8,  true,  true );     // read d0+2; gload d0+4; store d0+1
#pragma unroll 1
    for (int j = 0; j < 4; ++j) {     // steps 4..15 (stores d0+2 .. d0+13)
        STEP(1, 0, 10, true, true);
        STEP(2, 1, 10, true, true);
        STEP(0, 2, 10, true, true);
    }
    STEP(1, 0, 7,  false, true );     // read d0+15; store d0+14
    STEP(2, 0, 4,  false, true );     // read d0+16; store d0+15
#undef STEP
#undef GLOAD
}

extern "C" void kernel_launch(void* const* d_in, const int* in_sizes, int n_in,
                              void* d_out, int out_size, void* d_ws, size_t ws_size,
                              hipStream_t stream) {
    const float* x    = (const float*)d_in[0];
    const float* kern = (const float*)d_in[1];
    float*       out  = (float*)d_out;
    // 8 batches x 8 h-tiles(16 rows) x 8 d-chunks(16) = 512 blocks, 2 blocks/CU
    conv3d_circ_ldsp<<<dim3(512), dim3(256), 0, stream>>>(x, kern, out);
}

// Round 16
// 28.194 us; speedup vs baseline: 1.0227x; 1.0227x over previous
//
#include <hip/hip_runtime.h>

#define DIM   128
#define PLANE (DIM*DIM)
#define TD    16

typedef float vfloat4 __attribute__((ext_vector_type(4)));

__global__ __launch_bounds__(256, 2)   // min-waves 2 -> ~128-VGPR budget (256/SIMD heuristic)
void conv3d_circ_rp2(
    const float* __restrict__ x, const float* __restrict__ kern,
    float* __restrict__ out)
{
    const int tid = threadIdx.x;
    const int bid = blockIdx.x;
    const int b  = bid >> 6;          // 8 batches (8 ht x 8 dt = 64 blocks/batch)
    const int ht = (bid >> 3) & 7;    // 8 h-tiles of 16 rows
    const int dt = bid & 7;           // 8 d-chunks of 16 planes
    const int h0 = ht * 16;
    const int d0 = dt * TD;

    const int wq   = (tid & 31) * 4;        // 4 outputs along w; 32 lanes = full W
    const int hg   = h0 + (tid >> 5) * 2;   // this thread's 2 h rows: hg, hg+1
    const int lane = tid & 63;
    const int lleft  = (lane & 32) | ((lane - 1) & 31);  // wrap within 32-lane w-ring
    const int lright = (lane & 32) | ((lane + 1) & 31);

    // 4 tap rows: hg-1, hg, hg+1, hg+2 (wrapped)
    const int ro[4] = {((hg - 1) & (DIM - 1)) * DIM + wq,
                       hg * DIM + wq,
                       ((hg + 1) & (DIM - 1)) * DIM + wq,
                       ((hg + 2) & (DIM - 1)) * DIM + wq};

    float K0[9], K1[9], K2[9];        // uniform -> scalar loads -> SGPRs
#pragma unroll
    for (int i = 0; i < 9; ++i) { K0[i] = kern[i]; K1[i] = kern[9 + i]; K2[i] = kern[18 + i]; }

    const float* xb = x + (size_t)b * (DIM * PLANE);
    float* ob = out + (size_t)b * (DIM * PLANE) + (size_t)hg * DIM + wq;

    // Triple-buffered 4-row x 4-float register tiles; depth-2 plane prefetch.
    float rA[4][4], rB[4][4], rC[4][4];
    float accA[2][4], accB[2][4];     // accA -> out(p-1), accB -> out(p)
#pragma unroll
    for (int r = 0; r < 2; ++r)
#pragma unroll
        for (int j = 0; j < 4; ++j) { accA[r][j] = 0.f; accB[r][j] = 0.f; }

#define LOAD(R, P)                                                            \
    {                                                                         \
        const float* xp = xb + (size_t)(((P) & (DIM - 1)) * PLANE);           \
        _Pragma("unroll") for (int rr = 0; rr < 4; ++rr) {                    \
            const vfloat4 a = *(const vfloat4*)(xp + ro[rr]);                 \
            R[rr][0] = a.x; R[rr][1] = a.y; R[rr][2] = a.z; R[rr][3] = a.w;   \
        }                                                                     \
    }

    // Step I consumes plane p = d0-1+I (buffer I%3) and prefetches plane p+2
    // into buffer (I+2)%3 (freed at step I-1). K2->out(p-1), K1->out(p), K0->out(p+1).
#define STEP(RC_, RN_, I, DOLOAD)                                             \
    {                                                                         \
        const int p = d0 - 1 + (I);                                           \
        if (DOLOAD) LOAD(RN_, p + 2);                                         \
        float e[4][6];                                                        \
        _Pragma("unroll") for (int rr = 0; rr < 4; ++rr) {                    \
            e[rr][0] = __shfl(RC_[rr][3], lleft);   /* x[wq-1] */             \
            e[rr][1] = RC_[rr][0]; e[rr][2] = RC_[rr][1];                     \
            e[rr][3] = RC_[rr][2]; e[rr][4] = RC_[rr][3];                     \
            e[rr][5] = __shfl(RC_[rr][0], lright);  /* x[wq+4] */             \
        }                                                                     \
        float c0[2][4];                                                       \
        _Pragma("unroll") for (int r = 0; r < 2; ++r)                         \
        _Pragma("unroll") for (int j = 0; j < 4; ++j) c0[r][j] = 0.f;         \
        _Pragma("unroll") for (int ch = 0; ch < 3; ++ch)                      \
        _Pragma("unroll") for (int cw = 0; cw < 3; ++cw) {                    \
            const float k0 = K0[ch * 3 + cw];                                 \
            const float k1 = K1[ch * 3 + cw];                                 \
            const float k2 = K2[ch * 3 + cw];                                 \
            _Pragma("unroll") for (int r = 0; r < 2; ++r)                     \
            _Pragma("unroll") for (int j = 0; j < 4; ++j) {                   \
                const float xv = e[r + ch][j + cw];                           \
                accA[r][j] = fmaf(k2, xv, accA[r][j]);                        \
                accB[r][j] = fmaf(k1, xv, accB[r][j]);                        \
                c0[r][j]   = fmaf(k0, xv, c0[r][j]);                          \
            }                                                                 \
        }                                                                     \
        if ((I) >= 2) {                                                       \
            float* op = ob + (size_t)(p - 1) * PLANE;                         \
            _Pragma("unroll") for (int r = 0; r < 2; ++r) {                   \
                vfloat4 v;                                                    \
                v.x = accA[r][0]; v.y = accA[r][1];                           \
                v.z = accA[r][2]; v.w = accA[r][3];                           \
                __builtin_nontemporal_store(v, (vfloat4*)(op + r * DIM));     \
            }                                                                 \
        }                                                                     \
        _Pragma("unroll") for (int r = 0; r < 2; ++r)                        \
        _Pragma("unroll") for (int j = 0; j < 4; ++j)                         \
            { accA[r][j] = accB[r][j]; accB[r][j] = c0[r][j]; }               \
    }

    LOAD(rA, d0 - 1);      // plane for step 0
    LOAD(rB, d0);          // plane for step 1

    // TD=16: steps 0..17 (planes d0-1 .. d0+16); prefetches at steps 0..15
    // (step 15 loads plane d0+16, consumed at step 17); stores at steps 2..17.
#pragma unroll 1
    for (int i = 0; i < 15; i += 3) {
        STEP(rA, rC, i + 0, true);
        STEP(rB, rA, i + 1, true);
        STEP(rC, rB, i + 2, true);
    }
    STEP(rA, rC, 15, true);
    STEP(rB, rA, 16, false);
    STEP(rC, rB, 17, false);
#undef STEP
#undef LOAD
}

extern "C" void kernel_launch(void* const* d_in, const int* in_sizes, int n_in,
                              void* d_out, int out_size, void* d_ws, size_t ws_size,
                              hipStream_t stream) {
    const float* x    = (const float*)d_in[0];
    const float* kern = (const float*)d_in[1];
    float*       out  = (float*)d_out;
    // 8 batches x 8 h-tiles(16 rows) x 8 d-chunks(16) = 512 blocks, 2 blocks/CU
    conv3d_circ_rp2<<<dim3(512), dim3(256), 0, stream>>>(x, kern, out);
}

// Round 17
// 28.056 us; speedup vs baseline: 1.0277x; 1.0049x over previous
//
#include <hip/hip_runtime.h>

#define DIM   128
#define PLANE (DIM*DIM)
#define TD    16

typedef float vfloat4 __attribute__((ext_vector_type(4)));

__global__ __launch_bounds__(256, 4) void conv3d_circ_ring(
    const float* __restrict__ x, const float* __restrict__ kern,
    float* __restrict__ out)
{
    const int tid = threadIdx.x;
    const int bid = blockIdx.x;
    const int b  = bid >> 6;          // 8 batches (8 ht x 8 dt = 64 blocks/batch)
    const int ht = (bid >> 3) & 7;    // 8 h-tiles of 16 rows
    const int dt = bid & 7;           // 8 d-chunks of 16 planes
    const int h0 = ht * 16;
    const int d0 = dt * TD;

    const int wq   = (tid & 31) * 4;        // 4 outputs along w; 32 lanes = full W
    const int hg   = h0 + (tid >> 5) * 2;   // this thread's 2 h rows: hg, hg+1
    const int lane = tid & 63;
    const int lleft  = (lane & 32) | ((lane - 1) & 31);  // wrap within 32-lane w-ring
    const int lright = (lane & 32) | ((lane + 1) & 31);

    // 4 tap rows: hg-1, hg, hg+1, hg+2 (wrapped)
    const int ro[4] = {((hg - 1) & (DIM - 1)) * DIM + wq,
                       hg * DIM + wq,
                       ((hg + 1) & (DIM - 1)) * DIM + wq,
                       ((hg + 2) & (DIM - 1)) * DIM + wq};

    float K0[9], K1[9], K2[9];        // uniform -> scalar loads -> SGPRs
#pragma unroll
    for (int i = 0; i < 9; ++i) { K0[i] = kern[i]; K1[i] = kern[9 + i]; K2[i] = kern[18 + i]; }

    const float* xb = x + (size_t)b * (DIM * PLANE);
    float* ob = out + (size_t)b * (DIM * PLANE) + (size_t)hg * DIM + wq;

    // Double-buffered 4-row x 4-float register tiles (w-edges via shuffle at use).
    float rA[4][4], rB[4][4];
    // 3-bank rotating accumulators: bank(q) = (q - d0) mod 3. No shift movs.
    float a0[2][4], a1[2][4], a2[2][4];
#pragma unroll
    for (int r = 0; r < 2; ++r)
#pragma unroll
        for (int j = 0; j < 4; ++j) { a1[r][j] = 0.f; a2[r][j] = 0.f; }

#define LOAD(R, P)                                                            \
    {                                                                         \
        const float* xp = xb + (size_t)(((P) & (DIM - 1)) * PLANE);           \
        _Pragma("unroll") for (int rr = 0; rr < 4; ++rr) {                    \
            const vfloat4 a = *(const vfloat4*)(xp + ro[rr]);                 \
            R[rr][0] = a.x; R[rr][1] = a.y; R[rr][2] = a.z; R[rr][3] = a.w;   \
        }                                                                     \
    }

    // Step I consumes plane p = d0-1+I. AX += K2 (then stored -> out(p-1)),
    // AY += K1 (-> out(p)), AZ = K0-init (-> out(p+1), first contribution).
#define STEP(RC_, RN_, AX, AY, AZ, I, DOLOAD, DOSTORE)                        \
    {                                                                         \
        const int p = d0 - 1 + (I);                                           \
        if (DOLOAD) LOAD(RN_, p + 1);                                         \
        float e[4][6];                                                        \
        _Pragma("unroll") for (int rr = 0; rr < 4; ++rr) {                    \
            e[rr][0] = __shfl(RC_[rr][3], lleft);   /* x[wq-1] */             \
            e[rr][1] = RC_[rr][0]; e[rr][2] = RC_[rr][1];                     \
            e[rr][3] = RC_[rr][2]; e[rr][4] = RC_[rr][3];                     \
            e[rr][5] = __shfl(RC_[rr][0], lright);  /* x[wq+4] */             \
        }                                                                     \
        _Pragma("unroll") for (int ch = 0; ch < 3; ++ch)                      \
        _Pragma("unroll") for (int cw = 0; cw < 3; ++cw) {                    \
            const float k0 = K0[ch * 3 + cw];                                 \
            const float k1 = K1[ch * 3 + cw];                                 \
            const float k2 = K2[ch * 3 + cw];                                 \
            _Pragma("unroll") for (int r = 0; r < 2; ++r)                     \
            _Pragma("unroll") for (int j = 0; j < 4; ++j) {                   \
                const float xv = e[r + ch][j + cw];                           \
                AX[r][j] = fmaf(k2, xv, AX[r][j]);                            \
                AY[r][j] = fmaf(k1, xv, AY[r][j]);                            \
                if (ch == 0 && cw == 0) AZ[r][j] = k0 * xv;                   \
                else                    AZ[r][j] = fmaf(k0, xv, AZ[r][j]);    \
            }                                                                 \
        }                                                                     \
        if (DOSTORE) {                                                        \
            float* op = ob + (size_t)(p - 1) * PLANE;                         \
            _Pragma("unroll") for (int r = 0; r < 2; ++r) {                   \
                vfloat4 v;                                                    \
                v.x = AX[r][0]; v.y = AX[r][1];                               \
                v.z = AX[r][2]; v.w = AX[r][3];                               \
                __builtin_nontemporal_store(v, (vfloat4*)(op + r * DIM));     \
            }                                                                 \
        }                                                                     \
    }

    LOAD(rA, d0 - 1);

    // TD=16: 18 steps (planes d0-1 .. d0+16), stores at steps 2..17.
    STEP(rA, rB, a1, a2, a0,  0, true,  false);
    STEP(rB, rA, a2, a0, a1,  1, true,  false);
    STEP(rA, rB, a0, a1, a2,  2, true,  true );
    STEP(rB, rA, a1, a2, a0,  3, true,  true );
    STEP(rA, rB, a2, a0, a1,  4, true,  true );
    STEP(rB, rA, a0, a1, a2,  5, true,  true );
    STEP(rA, rB, a1, a2, a0,  6, true,  true );
    STEP(rB, rA, a2, a0, a1,  7, true,  true );
    STEP(rA, rB, a0, a1, a2,  8, true,  true );
    STEP(rB, rA, a1, a2, a0,  9, true,  true );
    STEP(rA, rB, a2, a0, a1, 10, true,  true );
    STEP(rB, rA, a0, a1, a2, 11, true,  true );
    STEP(rA, rB, a1, a2, a0, 12, true,  true );
    STEP(rB, rA, a2, a0, a1, 13, true,  true );
    STEP(rA, rB, a0, a1, a2, 14, true,  true );
    STEP(rB, rA, a1, a2, a0, 15, true,  true );
    STEP(rA, rB, a2, a0, a1, 16, true,  true );
    STEP(rB, rA, a0, a1, a2, 17, false, true );
#undef STEP
#undef LOAD
}

extern "C" void kernel_launch(void* const* d_in, const int* in_sizes, int n_in,
                              void* d_out, int out_size, void* d_ws, size_t ws_size,
                              hipStream_t stream) {
    const float* x    = (const float*)d_in[0];
    const float* kern = (const float*)d_in[1];
    float*       out  = (float*)d_out;
    // 8 batches x 8 h-tiles(16 rows) x 8 d-chunks(16) = 512 blocks, 2 blocks/CU
    conv3d_circ_ring<<<dim3(512), dim3(256), 0, stream>>>(x, kern, out);
}

// Round 18
// 26.972 us; speedup vs baseline: 1.0690x; 1.0402x over previous
//
#include <hip/hip_runtime.h>

#define DIM   128
#define PLANE (DIM*DIM)
#define TD    16

typedef float vfloat4 __attribute__((ext_vector_type(4)));

__global__ __launch_bounds__(256, 4) void conv3d_circ_td16(
    const float* __restrict__ x, const float* __restrict__ kern,
    float* __restrict__ out)
{
    const int tid = threadIdx.x;
    const int bid = blockIdx.x;
    const int b  = bid >> 6;          // 8 batches (8 ht x 8 dt = 64 blocks/batch)
    const int ht = (bid >> 3) & 7;    // 8 h-tiles of 16 rows
    const int dt = bid & 7;           // 8 d-chunks of 16 planes
    const int h0 = ht * 16;
    const int d0 = dt * TD;

    const int wq   = (tid & 31) * 4;        // 4 outputs along w; 32 lanes = full W
    const int hg   = h0 + (tid >> 5) * 2;   // this thread's 2 h rows: hg, hg+1
    const int lane = tid & 63;
    const int lleft  = (lane & 32) | ((lane - 1) & 31);  // wrap within 32-lane w-ring
    const int lright = (lane & 32) | ((lane + 1) & 31);

    // 4 tap rows: hg-1, hg, hg+1, hg+2 (wrapped)
    const int ro[4] = {((hg - 1) & (DIM - 1)) * DIM + wq,
                       hg * DIM + wq,
                       ((hg + 1) & (DIM - 1)) * DIM + wq,
                       ((hg + 2) & (DIM - 1)) * DIM + wq};

    float K0[9], K1[9], K2[9];        // uniform -> scalar loads -> SGPRs
#pragma unroll
    for (int i = 0; i < 9; ++i) { K0[i] = kern[i]; K1[i] = kern[9 + i]; K2[i] = kern[18 + i]; }

    const float* xb = x + (size_t)b * (DIM * PLANE);
    float* ob = out + (size_t)b * (DIM * PLANE) + (size_t)hg * DIM + wq;

    // Double-buffered 4-row x 4-float register tiles (w-edges via shuffle at use).
    float rA[4][4], rB[4][4];
    float accA[2][4], accB[2][4];     // accA -> out(p-1), accB -> out(p)
#pragma unroll
    for (int r = 0; r < 2; ++r)
#pragma unroll
        for (int j = 0; j < 4; ++j) { accA[r][j] = 0.f; accB[r][j] = 0.f; }

#define LOAD(R, P)                                                            \
    {                                                                         \
        const float* xp = xb + (size_t)(((P) & (DIM - 1)) * PLANE);           \
        _Pragma("unroll") for (int rr = 0; rr < 4; ++rr) {                    \
            const vfloat4 a = *(const vfloat4*)(xp + ro[rr]);                 \
            R[rr][0] = a.x; R[rr][1] = a.y; R[rr][2] = a.z; R[rr][3] = a.w;   \
        }                                                                     \
    }

    // Plane p contributes: K2 -> out(p-1), K1 -> out(p), K0 -> out(p+1).
#define STEP(RC, RN, I, DOLOAD)                                               \
    {                                                                         \
        const int p = d0 - 1 + (I);                                           \
        if (DOLOAD) LOAD(RN, p + 1);                                          \
        float e[4][6];                                                        \
        _Pragma("unroll") for (int rr = 0; rr < 4; ++rr) {                    \
            e[rr][0] = __shfl(RC[rr][3], lleft);   /* x[wq-1] */              \
            e[rr][1] = RC[rr][0]; e[rr][2] = RC[rr][1];                       \
            e[rr][3] = RC[rr][2]; e[rr][4] = RC[rr][3];                       \
            e[rr][5] = __shfl(RC[rr][0], lright);  /* x[wq+4] */              \
        }                                                                     \
        float c0[2][4];                                                       \
        _Pragma("unroll") for (int r = 0; r < 2; ++r)                         \
        _Pragma("unroll") for (int j = 0; j < 4; ++j) c0[r][j] = 0.f;         \
        _Pragma("unroll") for (int ch = 0; ch < 3; ++ch)                      \
        _Pragma("unroll") for (int cw = 0; cw < 3; ++cw) {                    \
            const float k0 = K0[ch * 3 + cw];                                 \
            const float k1 = K1[ch * 3 + cw];                                 \
            const float k2 = K2[ch * 3 + cw];                                 \
            _Pragma("unroll") for (int r = 0; r < 2; ++r)                     \
            _Pragma("unroll") for (int j = 0; j < 4; ++j) {                   \
                const float xv = e[r + ch][j + cw];                           \
                accA[r][j] = fmaf(k2, xv, accA[r][j]);                        \
                accB[r][j] = fmaf(k1, xv, accB[r][j]);                        \
                c0[r][j]   = fmaf(k0, xv, c0[r][j]);                          \
            }                                                                 \
        }                                                                     \
        if ((I) >= 2) {                                                       \
            float* op = ob + (size_t)(p - 1) * PLANE;                         \
            _Pragma("unroll") for (int r = 0; r < 2; ++r) {                   \
                vfloat4 v;                                                    \
                v.x = accA[r][0]; v.y = accA[r][1];                           \
                v.z = accA[r][2]; v.w = accA[r][3];                           \
                __builtin_nontemporal_store(v, (vfloat4*)(op + r * DIM));     \
            }                                                                 \
        }                                                                     \
        _Pragma("unroll") for (int r = 0; r < 2; ++r)                        \
        _Pragma("unroll") for (int j = 0; j < 4; ++j)                         \
            { accA[r][j] = accB[r][j]; accB[r][j] = c0[r][j]; }               \
    }

    LOAD(rA, d0 - 1);

    // TD=16: 18 steps (planes d0-1 .. d0+16), stores at steps 2..17.
#pragma unroll 1
    for (int i = 0; i < 16; i += 2) {
        STEP(rA, rB, i, true);
        STEP(rB, rA, i + 1, true);
    }
    STEP(rA, rB, 16, true);
    STEP(rB, rA, 17, false);
#undef STEP
#undef LOAD
}

extern "C" void kernel_launch(void* const* d_in, const int* in_sizes, int n_in,
                              void* d_out, int out_size, void* d_ws, size_t ws_size,
                              hipStream_t stream) {
    const float* x    = (const float*)d_in[0];
    const float* kern = (const float*)d_in[1];
    float*       out  = (float*)d_out;
    // 8 batches x 8 h-tiles(16 rows) x 8 d-chunks(16) = 512 blocks, 2 blocks/CU
    conv3d_circ_td16<<<dim3(512), dim3(256), 0, stream>>>(x, kern, out);
}